// Round 5
// baseline (773.710 us; speedup 1.0000x reference)
//
#include <hip/hip_runtime.h>

#define N_EDGES 400000
#define N_NODES 50000
#define ND 128
#define ED 64
#define MD 128
#define CAT 320
#define ET 64
#define MPITCH 136
#define EPITCH 72
#define H2PITCH 264

typedef unsigned short u16;
typedef __attribute__((ext_vector_type(8))) short bf16x8;
typedef __attribute__((ext_vector_type(4))) float f32x4;

__device__ __forceinline__ u16 f2bf(float f) {
  unsigned int x = __float_as_uint(f);
  unsigned int r = (x + 0x7fffu + ((x >> 16) & 1u)) >> 16;
  return (u16)r;
}
// load 8 consecutive f32, round-to-nearest-even to bf16x8
__device__ __forceinline__ bf16x8 ld8f(const float* p) {
  f32x4 a = *(const f32x4*)p;
  f32x4 b = *(const f32x4*)(p + 4);
  bf16x8 r;
  r[0] = (short)f2bf(a[0]); r[1] = (short)f2bf(a[1]);
  r[2] = (short)f2bf(a[2]); r[3] = (short)f2bf(a[3]);
  r[4] = (short)f2bf(b[0]); r[5] = (short)f2bf(b[1]);
  r[6] = (short)f2bf(b[2]); r[7] = (short)f2bf(b[3]);
  return r;
}
__device__ __forceinline__ int clampi(int v, int hi) {
  v = v < 0 ? 0 : v;
  return v >= hi ? hi - 1 : v;
}

// Load this block's 64 src + 64 dst indices into sIdx, auto-detecting int32 vs
// int64 storage (odd 32-bit words all zero <=> int64). Proven int32 in R4
// (R3==R4 bit-identical), kept as cheap insurance.
__device__ __forceinline__ void load_indices(
    int* sIdx, int* sFlag, const void* idxRaw, int eb, int tid)
{
  if (tid < ET) {
    unsigned w = ((const unsigned*)idxRaw)[2u * (unsigned)(eb + tid) + 1u];
    int any32 = __any(w != 0u);
    if (tid == 0) *sFlag = any32;   // nonzero -> int32 layout
  }
  __syncthreads();
  const bool is32 = (*sFlag != 0);
  if (tid < ET) {
    int v = is32 ? ((const int*)idxRaw)[eb + tid]
                 : (int)((const long long*)idxRaw)[eb + tid];
    sIdx[tid] = clampi(v, N_NODES);
  } else if (tid < 2 * ET) {
    int t = tid - ET;
    int v = is32 ? ((const int*)idxRaw)[N_EDGES + eb + t]
                 : (int)((const long long*)idxRaw)[(size_t)N_EDGES + eb + t];
    sIdx[tid] = clampi(v, N_NODES);
  }
  __syncthreads();
}

// Gather h = [nf[src](128) | nf[dst](128) | ef(64)] into sH (bf16),
// 40 x 8-elem chunks per edge, XOR-swizzled (chunk ^= edge&7).
__device__ __forceinline__ void gather_h(
    u16* sH, const int* sIdx, const float* __restrict__ nf,
    const float* __restrict__ ef, int eb, int tid)
{
#pragma unroll
  for (int i = 0; i < 10; ++i) {
    unsigned g = i * 256 + tid;
    unsigned e = g / 40u;
    unsigned c = g - e * 40u;
    const float* p;
    if (c < 16u)       p = nf + (size_t)sIdx[e] * ND + c * 8u;
    else if (c < 32u)  p = nf + (size_t)sIdx[ET + e] * ND + (c - 16u) * 8u;
    else               p = ef + (size_t)(eb + e) * ED + (c - 32u) * 8u;
    bf16x8 v = ld8f(p);
    unsigned pc = c ^ (e & 7u);
    *(bf16x8*)&sH[e * CAT + pc * 8u] = v;
  }
}

// ---------------- Kernel A: message path, 64 edges/block ----------------
__global__ __launch_bounds__(256, 2) void edge_msg_kernel(
    const float* __restrict__ nf, const float* __restrict__ ef,
    const void* __restrict__ idxRaw,
    const float* __restrict__ Wm1, const float* __restrict__ bm1,
    const float* __restrict__ Wm2, const float* __restrict__ bm2,
    const float* __restrict__ Wm3, const float* __restrict__ bm3,
    float* __restrict__ msg)
{
  __shared__ __align__(16) u16 sH[ET * CAT];       // 40960 B
  __shared__ __align__(16) u16 sC[ET * MPITCH];    // 17408 B
  __shared__ int sIdx[2 * ET];
  __shared__ int sFlag;
  u16* sM1 = sH;  // m1 aliases sH after GEMM1 (barrier-protected)

  const int tid  = threadIdx.x;
  const int lane = tid & 63;
  const int wave = tid >> 6;
  const int l15  = lane & 15;
  const int quad = lane >> 4;
  const int eb   = blockIdx.x * ET;

  load_indices(sIdx, &sFlag, idxRaw, eb, tid);
  gather_h(sH, sIdx, nf, ef, eb, tid);
  __syncthreads();

  // GEMM1: m1 = relu(h @ Wm1^T + bm1), N=128, K=320
  f32x4 acc1[2][4] = {};
  for (int kk = 0; kk < 10; ++kk) {
    int ko = kk * 32 + quad * 8;
    unsigned cc = (unsigned)(ko >> 3);
    bf16x8 a[4];
#pragma unroll
    for (int m = 0; m < 4; ++m) {
      unsigned e = (unsigned)(m * 16 + l15);
      a[m] = *(const bf16x8*)&sH[e * CAT + (cc ^ (e & 7u)) * 8u];
    }
#pragma unroll
    for (int i = 0; i < 2; ++i) {
      int f = (2 * wave + i) * 16 + l15;
      bf16x8 b = ld8f(Wm1 + (size_t)f * CAT + ko);
#pragma unroll
      for (int m = 0; m < 4; ++m)
        acc1[i][m] = __builtin_amdgcn_mfma_f32_16x16x32_bf16(a[m], b, acc1[i][m], 0, 0, 0);
    }
  }
  __syncthreads();  // all sH reads done before aliased m1 writes

#pragma unroll
  for (int i = 0; i < 2; ++i) {
    int f = (2 * wave + i) * 16 + l15;
    float bias = bm1[f];
#pragma unroll
    for (int m = 0; m < 4; ++m)
#pragma unroll
      for (int r = 0; r < 4; ++r) {
        int row = m * 16 + quad * 4 + r;
        float v = acc1[i][m][r] + bias;
        sM1[row * MPITCH + f] = f2bf(v > 0.f ? v : 0.f);
      }
  }
  __syncthreads();

  // GEMM2: m2 = relu(m1 @ Wm2^T + bm2) -> sC, N=128, K=128
  f32x4 acc2[2][4] = {};
  for (int kk = 0; kk < 4; ++kk) {
    int ko = kk * 32 + quad * 8;
    bf16x8 a[4];
#pragma unroll
    for (int m = 0; m < 4; ++m)
      a[m] = *(const bf16x8*)&sM1[(m * 16 + l15) * MPITCH + ko];
#pragma unroll
    for (int i = 0; i < 2; ++i) {
      int f = (2 * wave + i) * 16 + l15;
      bf16x8 b = ld8f(Wm2 + (size_t)f * MD + ko);
#pragma unroll
      for (int m = 0; m < 4; ++m)
        acc2[i][m] = __builtin_amdgcn_mfma_f32_16x16x32_bf16(a[m], b, acc2[i][m], 0, 0, 0);
    }
  }
#pragma unroll
  for (int i = 0; i < 2; ++i) {
    int f = (2 * wave + i) * 16 + l15;
    float bias = bm2[f];
#pragma unroll
    for (int m = 0; m < 4; ++m)
#pragma unroll
      for (int r = 0; r < 4; ++r) {
        int row = m * 16 + quad * 4 + r;
        float v = acc2[i][m][r] + bias;
        sC[row * MPITCH + f] = f2bf(v > 0.f ? v : 0.f);
      }
  }
  __syncthreads();

  // GEMM3: m3 = m2 @ Wm3^T + bm3 ; scatter-add to msg[dst]
  f32x4 acc3[2][4] = {};
  for (int kk = 0; kk < 4; ++kk) {
    int ko = kk * 32 + quad * 8;
    bf16x8 a[4];
#pragma unroll
    for (int m = 0; m < 4; ++m)
      a[m] = *(const bf16x8*)&sC[(m * 16 + l15) * MPITCH + ko];
#pragma unroll
    for (int i = 0; i < 2; ++i) {
      int f = (2 * wave + i) * 16 + l15;
      bf16x8 b = ld8f(Wm3 + (size_t)f * MD + ko);
#pragma unroll
      for (int m = 0; m < 4; ++m)
        acc3[i][m] = __builtin_amdgcn_mfma_f32_16x16x32_bf16(a[m], b, acc3[i][m], 0, 0, 0);
    }
  }
#pragma unroll
  for (int i = 0; i < 2; ++i) {
    int f = (2 * wave + i) * 16 + l15;
    float bias = bm3[f];
#pragma unroll
    for (int m = 0; m < 4; ++m)
#pragma unroll
      for (int r = 0; r < 4; ++r) {
        int row = m * 16 + quad * 4 + r;
        int d = sIdx[ET + row];
        atomicAdd(&msg[(size_t)d * MD + f], acc3[i][m][r] + bias);
      }
  }
}

// ---------------- Kernel B: node update, 64 nodes/block ----------------
__global__ __launch_bounds__(256, 4) void node_kernel(
    const float* __restrict__ nf, const float* __restrict__ msg,
    const float* __restrict__ Wn, const float* __restrict__ bn,
    const float* __restrict__ gamma, const float* __restrict__ beta,
    float* __restrict__ outN)
{
  __shared__ __align__(16) u16 sH[ET * H2PITCH];   // 33792 B
  __shared__ float sPart[4][ET][2];                // 2048 B

  const int tid  = threadIdx.x;
  const int lane = tid & 63;
  const int wave = tid >> 6;
  const int l15  = lane & 15;
  const int quad = lane >> 4;
  const int nb   = blockIdx.x * ET;

#pragma unroll
  for (int i = 0; i < 8; ++i) {
    int g = i * 256 + tid;
    int r = g >> 5;
    int c = g & 31;
    int node = nb + r;
    bool valid = node < N_NODES;
    bf16x8 v = {};
    if (c < 16) {
      if (valid) v = ld8f(nf + (size_t)node * ND + c * 8);
      *(bf16x8*)&sH[r * H2PITCH + c * 8] = v;
    } else {
      int co = (c - 16) * 8;
      if (valid) v = ld8f(msg + (size_t)node * MD + co);
      *(bf16x8*)&sH[r * H2PITCH + ND + co] = v;
    }
  }
  __syncthreads();

  // GEMM: u_pre = [nf|msg][64x256] @ Wn^T
  f32x4 acc[2][4] = {};
  for (int kk = 0; kk < 8; ++kk) {
    int ko = kk * 32 + quad * 8;
    bf16x8 a[4];
#pragma unroll
    for (int m = 0; m < 4; ++m)
      a[m] = *(const bf16x8*)&sH[(m * 16 + l15) * H2PITCH + ko];
#pragma unroll
    for (int i = 0; i < 2; ++i) {
      int f = (2 * wave + i) * 16 + l15;
      bf16x8 b = ld8f(Wn + (size_t)f * 256 + ko);
#pragma unroll
      for (int m = 0; m < 4; ++m)
        acc[i][m] = __builtin_amdgcn_mfma_f32_16x16x32_bf16(a[m], b, acc[i][m], 0, 0, 0);
    }
  }

  // u = relu(acc + bias) in-register
#pragma unroll
  for (int i = 0; i < 2; ++i) {
    int f = (2 * wave + i) * 16 + l15;
    float bias = bn[f];
#pragma unroll
    for (int m = 0; m < 4; ++m)
#pragma unroll
      for (int r = 0; r < 4; ++r) {
        float v = acc[i][m][r] + bias;
        acc[i][m][r] = v > 0.f ? v : 0.f;
      }
  }

  // per-row partial (sum, sumsq) over this wave's 32 cols
#pragma unroll
  for (int m = 0; m < 4; ++m)
#pragma unroll
    for (int r = 0; r < 4; ++r) {
      float p = acc[0][m][r] + acc[1][m][r];
      float q = acc[0][m][r] * acc[0][m][r] + acc[1][m][r] * acc[1][m][r];
#pragma unroll
      for (int mk = 1; mk < 16; mk <<= 1) {
        p += __shfl_xor(p, mk);
        q += __shfl_xor(q, mk);
      }
      if (l15 == 0) {
        int row = m * 16 + quad * 4 + r;
        sPart[wave][row][0] = p;
        sPart[wave][row][1] = q;
      }
    }
  __syncthreads();

  // combine across waves, normalize, store (f32 output)
#pragma unroll
  for (int m = 0; m < 4; ++m)
#pragma unroll
    for (int r = 0; r < 4; ++r) {
      int row = m * 16 + quad * 4 + r;
      float ts  = sPart[0][row][0] + sPart[1][row][0] + sPart[2][row][0] + sPart[3][row][0];
      float tss = sPart[0][row][1] + sPart[1][row][1] + sPart[2][row][1] + sPart[3][row][1];
      float mu  = ts * 0.0078125f;
      float var = tss * 0.0078125f - mu * mu;
      var = var > 0.f ? var : 0.f;
      float rstd = rsqrtf(var + 1e-5f);
      int node = nb + row;
      if (node < N_NODES) {
#pragma unroll
        for (int i = 0; i < 2; ++i) {
          int f = (2 * wave + i) * 16 + l15;
          float o = (acc[i][m][r] - mu) * rstd * gamma[f] + beta[f];
          outN[(size_t)node * ND + f] = o;
        }
      }
    }
}

// ---------------- Kernel C: edge-update path, 64 edges/block ----------------
__global__ __launch_bounds__(256, 3) void edge_out_kernel(
    const float* __restrict__ nf, const float* __restrict__ ef,
    const void* __restrict__ idxRaw,
    const float* __restrict__ We1, const float* __restrict__ be1,
    const float* __restrict__ We2, const float* __restrict__ be2,
    float* __restrict__ outE)
{
  __shared__ __align__(16) u16 sH[ET * CAT];       // 40960 B
  __shared__ __align__(16) u16 sE1[ET * EPITCH];   // 9216 B
  __shared__ int sIdx[2 * ET];
  __shared__ int sFlag;

  const int tid  = threadIdx.x;
  const int lane = tid & 63;
  const int wave = tid >> 6;
  const int l15  = lane & 15;
  const int quad = lane >> 4;
  const int eb   = blockIdx.x * ET;

  load_indices(sIdx, &sFlag, idxRaw, eb, tid);
  gather_h(sH, sIdx, nf, ef, eb, tid);
  __syncthreads();

  // GEMM1e: e1 = relu(h @ We1^T + be1), N=64 (one 16-tile per wave), K=320
  f32x4 acc[4] = {};
  const int f = wave * 16 + l15;
  for (int kk = 0; kk < 10; ++kk) {
    int ko = kk * 32 + quad * 8;
    unsigned cc = (unsigned)(ko >> 3);
    bf16x8 b = ld8f(We1 + (size_t)f * CAT + ko);
#pragma unroll
    for (int m = 0; m < 4; ++m) {
      unsigned e = (unsigned)(m * 16 + l15);
      bf16x8 a = *(const bf16x8*)&sH[e * CAT + (cc ^ (e & 7u)) * 8u];
      acc[m] = __builtin_amdgcn_mfma_f32_16x16x32_bf16(a, b, acc[m], 0, 0, 0);
    }
  }
  {
    float bias = be1[f];
#pragma unroll
    for (int m = 0; m < 4; ++m)
#pragma unroll
      for (int r = 0; r < 4; ++r) {
        int row = m * 16 + quad * 4 + r;
        float v = acc[m][r] + bias;
        sE1[row * EPITCH + f] = f2bf(v > 0.f ? v : 0.f);
      }
  }
  __syncthreads();

  // GEMM2e: e2 = e1 @ We2^T + be2, N=64, K=64 -> f32 output
  f32x4 acc2[4] = {};
  for (int kk = 0; kk < 2; ++kk) {
    int ko = kk * 32 + quad * 8;
    bf16x8 b = ld8f(We2 + (size_t)f * ED + ko);
#pragma unroll
    for (int m = 0; m < 4; ++m) {
      bf16x8 a = *(const bf16x8*)&sE1[(m * 16 + l15) * EPITCH + ko];
      acc2[m] = __builtin_amdgcn_mfma_f32_16x16x32_bf16(a, b, acc2[m], 0, 0, 0);
    }
  }
  {
    float bias = be2[f];
#pragma unroll
    for (int m = 0; m < 4; ++m)
#pragma unroll
      for (int r = 0; r < 4; ++r) {
        int row = m * 16 + quad * 4 + r;
        outE[(size_t)(eb + row) * ED + f] = acc2[m][r] + bias;
      }
  }
}

extern "C" void kernel_launch(void* const* d_in, const int* in_sizes, int n_in,
                              void* d_out, int out_size, void* d_ws, size_t ws_size,
                              hipStream_t stream)
{
  const float* nf  = (const float*)d_in[0];
  const float* ef  = (const float*)d_in[1];
  const void*  ei  = d_in[2];
  const float* Wm1 = (const float*)d_in[3];
  const float* bm1 = (const float*)d_in[4];
  const float* Wm2 = (const float*)d_in[5];
  const float* bm2 = (const float*)d_in[6];
  const float* Wm3 = (const float*)d_in[7];
  const float* bm3 = (const float*)d_in[8];
  const float* We1 = (const float*)d_in[9];
  const float* be1 = (const float*)d_in[10];
  const float* We2 = (const float*)d_in[11];
  const float* be2 = (const float*)d_in[12];
  const float* Wn  = (const float*)d_in[13];
  const float* bn  = (const float*)d_in[14];
  const float* gamma = (const float*)d_in[15];
  const float* beta  = (const float*)d_in[16];

  float* outN = (float*)d_out;                           // [50000,128] f32
  float* outE = outN + (size_t)N_NODES * ND;             // [400000,64] f32
  // f32 message accumulator in the head of the edge-output region
  // (25.6 MB of its 102.4 MB); node_kernel consumes it, then
  // edge_out_kernel overwrites the region. Stream-ordered. No d_ws needed.
  float* msg = outE;

  hipMemsetAsync(msg, 0, (size_t)N_NODES * MD * sizeof(float), stream);
  edge_msg_kernel<<<N_EDGES / ET, 256, 0, stream>>>(
      nf, ef, ei, Wm1, bm1, Wm2, bm2, Wm3, bm3, msg);
  node_kernel<<<(N_NODES + ET - 1) / ET, 256, 0, stream>>>(
      nf, msg, Wn, bn, gamma, beta, outN);
  edge_out_kernel<<<N_EDGES / ET, 256, 0, stream>>>(
      nf, ef, ei, We1, be1, We2, be2, outE);
}

// Round 6
// 621.912 us; speedup vs baseline: 1.2441x; 1.2441x over previous
//
#include <hip/hip_runtime.h>

#define N_EDGES 400000
#define N_NODES 50000
#define ND 128
#define ED 64
#define MD 128
#define CAT 320
#define ET 64
#define MPITCH 136
#define EPITCH 72
#define H2PITCH 264

typedef unsigned short u16;
typedef __attribute__((ext_vector_type(8))) short bf16x8;
typedef __attribute__((ext_vector_type(4))) float f32x4;

// ---- ws layout (u16 element offsets) ----
#define WS_WM1 0         // 128*320
#define WS_WM2 40960     // 128*128
#define WS_WM3 57344     // 128*128
#define WS_WE1 73728     // 64*320
#define WS_WE2 94208     // 64*64
#define WS_WN  98304     // 128*256
#define WS_WEND 131072   // = 262144 bytes
#define WS_NFB 131072    // node features bf16: 50000*128 u16
#define WS_FULL_BYTES (2u * (WS_NFB + N_NODES * ND))  // 13,369,344 B

__device__ __forceinline__ u16 f2bf(float f) {
  unsigned int x = __float_as_uint(f);
  unsigned int r = (x + 0x7fffu + ((x >> 16) & 1u)) >> 16;
  return (u16)r;
}
__device__ __forceinline__ bf16x8 ld8f(const float* p) {
  f32x4 a = *(const f32x4*)p;
  f32x4 b = *(const f32x4*)(p + 4);
  bf16x8 r;
  r[0] = (short)f2bf(a[0]); r[1] = (short)f2bf(a[1]);
  r[2] = (short)f2bf(a[2]); r[3] = (short)f2bf(a[3]);
  r[4] = (short)f2bf(b[0]); r[5] = (short)f2bf(b[1]);
  r[6] = (short)f2bf(b[2]); r[7] = (short)f2bf(b[3]);
  return r;
}
template<bool WB>
__device__ __forceinline__ bf16x8 ldw(const void* w, size_t off) {
  if (WB) return *(const bf16x8*)((const u16*)w + off);
  else    return ld8f((const float*)w + off);
}
__device__ __forceinline__ int clampi(int v, int hi) {
  v = v < 0 ? 0 : v;
  return v >= hi ? hi - 1 : v;
}

// ---------------- prep: weights f32 -> bf16 into ws ----------------
__global__ __launch_bounds__(256) void prep_weights(
    const float* __restrict__ Wm1, const float* __restrict__ Wm2,
    const float* __restrict__ Wm3, const float* __restrict__ We1,
    const float* __restrict__ We2, const float* __restrict__ Wn,
    u16* __restrict__ ws)
{
  int i = blockIdx.x * 256 + threadIdx.x;   // grid covers WS_WEND
  if (i >= WS_WEND) return;
  const float* s; int off;
  if      (i < WS_WM2) { s = Wm1; off = WS_WM1; }
  else if (i < WS_WM3) { s = Wm2; off = WS_WM2; }
  else if (i < WS_WE1) { s = Wm3; off = WS_WM3; }
  else if (i < WS_WE2) { s = We1; off = WS_WE1; }
  else if (i < WS_WN)  { s = We2; off = WS_WE2; }
  else                 { s = Wn;  off = WS_WN;  }
  ws[i] = f2bf(s[i - off]);
}

// ---------------- prep: node features f32 -> bf16 into ws ----------------
__global__ __launch_bounds__(256) void prep_nf(
    const float* __restrict__ nf, u16* __restrict__ nfb)
{
  size_t t = ((size_t)blockIdx.x * 256 + threadIdx.x) * 8;
  if (t >= (size_t)N_NODES * ND) return;
  *(bf16x8*)(nfb + t) = ld8f(nf + t);
}

// Load 64 src + 64 dst indices (int32/int64 auto-detect, proven int32).
__device__ __forceinline__ void load_indices(
    int* sIdx, int* sFlag, const void* idxRaw, int eb, int tid)
{
  if (tid < ET) {
    unsigned w = ((const unsigned*)idxRaw)[2u * (unsigned)(eb + tid) + 1u];
    int any32 = __any(w != 0u);
    if (tid == 0) *sFlag = any32;
  }
  __syncthreads();
  const bool is32 = (*sFlag != 0);
  if (tid < ET) {
    int v = is32 ? ((const int*)idxRaw)[eb + tid]
                 : (int)((const long long*)idxRaw)[eb + tid];
    sIdx[tid] = clampi(v, N_NODES);
  } else if (tid < 2 * ET) {
    int t = tid - ET;
    int v = is32 ? ((const int*)idxRaw)[N_EDGES + eb + t]
                 : (int)((const long long*)idxRaw)[(size_t)N_EDGES + eb + t];
    sIdx[tid] = clampi(v, N_NODES);
  }
  __syncthreads();
}

// Gather h = [nf[src] | nf[dst] | ef] into sH (bf16), XOR-swizzled chunks.
template<bool NB>
__device__ __forceinline__ void gather_h(
    u16* sH, const int* sIdx, const float* __restrict__ nf,
    const u16* __restrict__ nfb, const float* __restrict__ ef,
    int eb, int tid)
{
#pragma unroll
  for (int i = 0; i < 10; ++i) {
    unsigned g = i * 256 + tid;
    unsigned e = g / 40u;
    unsigned c = g - e * 40u;
    bf16x8 v;
    if (c < 32u) {
      int node = sIdx[(c < 16u) ? e : (ET + e)];
      unsigned cc = c & 15u;
      if (NB) v = *(const bf16x8*)(nfb + (size_t)node * ND + cc * 8u);
      else    v = ld8f(nf + (size_t)node * ND + cc * 8u);
    } else {
      v = ld8f(ef + (size_t)(eb + e) * ED + (c - 32u) * 8u);
    }
    unsigned pc = c ^ (e & 7u);
    *(bf16x8*)&sH[e * CAT + pc * 8u] = v;
  }
}

// ---------------- Fused edge kernel: msg path + edge path ----------------
template<bool WB, bool NB>
__global__ __launch_bounds__(256, 3) void edge_fused_kernel(
    const float* __restrict__ nf, const u16* __restrict__ nfb,
    const float* __restrict__ ef, const void* __restrict__ idxRaw,
    const void* __restrict__ wm1, const float* __restrict__ bm1,
    const void* __restrict__ wm2, const float* __restrict__ bm2,
    const void* __restrict__ wm3, const float* __restrict__ bm3,
    const void* __restrict__ we1, const float* __restrict__ be1,
    const void* __restrict__ we2, const float* __restrict__ be2,
    float* __restrict__ msg, float* __restrict__ outE)
{
  __shared__ __align__(16) u16 sH[ET * CAT];   // 40960 B, aliased below
  __shared__ int sIdx[2 * ET];
  __shared__ int sFlag;
  u16* sM = sH;                 // m1 (then m2): 64 x MPITCH = 17408 B
  u16* sE1 = sH + ET * MPITCH;  // e1: 64 x EPITCH = 9216 B (ends 26624 < 40960)

  const int tid  = threadIdx.x;
  const int lane = tid & 63;
  const int wave = tid >> 6;
  const int l15  = lane & 15;
  const int quad = lane >> 4;
  const int eb   = blockIdx.x * ET;

  load_indices(sIdx, &sFlag, idxRaw, eb, tid);
  gather_h<NB>(sH, sIdx, nf, nfb, ef, eb, tid);
  __syncthreads();

  // ---- GEMM1: h[64x320] @ {Wm1^T | We1^T} -> m1[64x128], e1[64x64]
  // 12 n-tiles (0..7 -> m1, 8..11 -> e1), 3 per wave.
  f32x4 acc1[3][4] = {};
  for (int kk = 0; kk < 10; ++kk) {
    int ko = kk * 32 + quad * 8;
    unsigned cc = (unsigned)(ko >> 3);
    bf16x8 a[4];
#pragma unroll
    for (int m = 0; m < 4; ++m) {
      unsigned e = (unsigned)(m * 16 + l15);
      a[m] = *(const bf16x8*)&sH[e * CAT + (cc ^ (e & 7u)) * 8u];
    }
#pragma unroll
    for (int i = 0; i < 3; ++i) {
      int nt = 3 * wave + i;
      int f = nt * 16 + l15;
      bf16x8 b = (nt < 8) ? ldw<WB>(wm1, (size_t)f * CAT + ko)
                          : ldw<WB>(we1, (size_t)(f - ND) * CAT + ko);
#pragma unroll
      for (int m = 0; m < 4; ++m)
        acc1[i][m] = __builtin_amdgcn_mfma_f32_16x16x32_bf16(a[m], b, acc1[i][m], 0, 0, 0);
    }
  }
  __syncthreads();  // all sH reads done before aliased m1/e1 writes

#pragma unroll
  for (int i = 0; i < 3; ++i) {
    int nt = 3 * wave + i;
    int f = nt * 16 + l15;
    float bias = (nt < 8) ? bm1[f] : be1[f - ND];
#pragma unroll
    for (int m = 0; m < 4; ++m)
#pragma unroll
      for (int r = 0; r < 4; ++r) {
        int row = m * 16 + quad * 4 + r;
        float v = acc1[i][m][r] + bias;
        v = v > 0.f ? v : 0.f;
        if (nt < 8) sM[row * MPITCH + f] = f2bf(v);
        else        sE1[row * EPITCH + (f - ND)] = f2bf(v);
      }
  }
  __syncthreads();

  // ---- GEMM2e: e2 = e1 @ We2^T + be2 -> outE (f32). 1 n-tile per wave.
  {
    f32x4 acc[4] = {};
    const int f = wave * 16 + l15;
    for (int kk = 0; kk < 2; ++kk) {
      int ko = kk * 32 + quad * 8;
      bf16x8 b = ldw<WB>(we2, (size_t)f * ED + ko);
#pragma unroll
      for (int m = 0; m < 4; ++m) {
        bf16x8 a = *(const bf16x8*)&sE1[(m * 16 + l15) * EPITCH + ko];
        acc[m] = __builtin_amdgcn_mfma_f32_16x16x32_bf16(a, b, acc[m], 0, 0, 0);
      }
    }
    float bias = be2[f];
#pragma unroll
    for (int m = 0; m < 4; ++m)
#pragma unroll
      for (int r = 0; r < 4; ++r) {
        int row = m * 16 + quad * 4 + r;
        outE[(size_t)(eb + row) * ED + f] = acc[m][r] + bias;
      }
  }

  // ---- GEMM2m: m2 = relu(m1 @ Wm2^T + bm2), accumulate in regs
  f32x4 acc2[2][4] = {};
  for (int kk = 0; kk < 4; ++kk) {
    int ko = kk * 32 + quad * 8;
    bf16x8 a[4];
#pragma unroll
    for (int m = 0; m < 4; ++m)
      a[m] = *(const bf16x8*)&sM[(m * 16 + l15) * MPITCH + ko];
#pragma unroll
    for (int i = 0; i < 2; ++i) {
      int f = (2 * wave + i) * 16 + l15;
      bf16x8 b = ldw<WB>(wm2, (size_t)f * MD + ko);
#pragma unroll
      for (int m = 0; m < 4; ++m)
        acc2[i][m] = __builtin_amdgcn_mfma_f32_16x16x32_bf16(a[m], b, acc2[i][m], 0, 0, 0);
    }
  }
  __syncthreads();  // all m1 reads done before overwrite with m2

#pragma unroll
  for (int i = 0; i < 2; ++i) {
    int f = (2 * wave + i) * 16 + l15;
    float bias = bm2[f];
#pragma unroll
    for (int m = 0; m < 4; ++m)
#pragma unroll
      for (int r = 0; r < 4; ++r) {
        int row = m * 16 + quad * 4 + r;
        float v = acc2[i][m][r] + bias;
        sM[row * MPITCH + f] = f2bf(v > 0.f ? v : 0.f);
      }
  }
  __syncthreads();

  // ---- GEMM3: m3 = m2 @ Wm3^T + bm3 ; scatter-add to msg[dst]
  f32x4 acc3[2][4] = {};
  for (int kk = 0; kk < 4; ++kk) {
    int ko = kk * 32 + quad * 8;
    bf16x8 a[4];
#pragma unroll
    for (int m = 0; m < 4; ++m)
      a[m] = *(const bf16x8*)&sM[(m * 16 + l15) * MPITCH + ko];
#pragma unroll
    for (int i = 0; i < 2; ++i) {
      int f = (2 * wave + i) * 16 + l15;
      bf16x8 b = ldw<WB>(wm3, (size_t)f * MD + ko);
#pragma unroll
      for (int m = 0; m < 4; ++m)
        acc3[i][m] = __builtin_amdgcn_mfma_f32_16x16x32_bf16(a[m], b, acc3[i][m], 0, 0, 0);
    }
  }
#pragma unroll
  for (int i = 0; i < 2; ++i) {
    int f = (2 * wave + i) * 16 + l15;
    float bias = bm3[f];
#pragma unroll
    for (int m = 0; m < 4; ++m)
#pragma unroll
      for (int r = 0; r < 4; ++r) {
        int row = m * 16 + quad * 4 + r;
        int d = sIdx[ET + row];
        atomicAdd(&msg[(size_t)d * MD + f], acc3[i][m][r] + bias);
      }
  }
}

// ---------------- Node kernel: 64 nodes/block ----------------
// msg lives in the outN region; all msg reads staged before outN writes
// (block-diagonal: block b touches only rows [64b, 64b+64)).
template<bool WB, bool NB>
__global__ __launch_bounds__(256, 4) void node_kernel(
    const float* __restrict__ nf, const u16* __restrict__ nfb,
    const float* __restrict__ msg,
    const void* __restrict__ wn, const float* __restrict__ bn,
    const float* __restrict__ gamma, const float* __restrict__ beta,
    float* __restrict__ outN)
{
  __shared__ __align__(16) u16 sH[ET * H2PITCH];   // 33792 B
  __shared__ float sPart[4][ET][2];                // 2048 B

  const int tid  = threadIdx.x;
  const int lane = tid & 63;
  const int wave = tid >> 6;
  const int l15  = lane & 15;
  const int quad = lane >> 4;
  const int nb   = blockIdx.x * ET;

#pragma unroll
  for (int i = 0; i < 8; ++i) {
    int g = i * 256 + tid;
    int r = g >> 5;
    int c = g & 31;
    int node = nb + r;
    bool valid = node < N_NODES;
    bf16x8 v = {};
    if (c < 16) {
      if (valid) {
        if (NB) v = *(const bf16x8*)(nfb + (size_t)node * ND + c * 8);
        else    v = ld8f(nf + (size_t)node * ND + c * 8);
      }
      *(bf16x8*)&sH[r * H2PITCH + c * 8] = v;
    } else {
      int co = (c - 16) * 8;
      if (valid) v = ld8f(msg + (size_t)node * MD + co);
      *(bf16x8*)&sH[r * H2PITCH + ND + co] = v;
    }
  }
  __syncthreads();

  f32x4 acc[2][4] = {};
  for (int kk = 0; kk < 8; ++kk) {
    int ko = kk * 32 + quad * 8;
    bf16x8 a[4];
#pragma unroll
    for (int m = 0; m < 4; ++m)
      a[m] = *(const bf16x8*)&sH[(m * 16 + l15) * H2PITCH + ko];
#pragma unroll
    for (int i = 0; i < 2; ++i) {
      int f = (2 * wave + i) * 16 + l15;
      bf16x8 b = ldw<WB>(wn, (size_t)f * 256 + ko);
#pragma unroll
      for (int m = 0; m < 4; ++m)
        acc[i][m] = __builtin_amdgcn_mfma_f32_16x16x32_bf16(a[m], b, acc[i][m], 0, 0, 0);
    }
  }

#pragma unroll
  for (int i = 0; i < 2; ++i) {
    int f = (2 * wave + i) * 16 + l15;
    float bias = bn[f];
#pragma unroll
    for (int m = 0; m < 4; ++m)
#pragma unroll
      for (int r = 0; r < 4; ++r) {
        float v = acc[i][m][r] + bias;
        acc[i][m][r] = v > 0.f ? v : 0.f;
      }
  }

#pragma unroll
  for (int m = 0; m < 4; ++m)
#pragma unroll
    for (int r = 0; r < 4; ++r) {
      float p = acc[0][m][r] + acc[1][m][r];
      float q = acc[0][m][r] * acc[0][m][r] + acc[1][m][r] * acc[1][m][r];
#pragma unroll
      for (int mk = 1; mk < 16; mk <<= 1) {
        p += __shfl_xor(p, mk);
        q += __shfl_xor(q, mk);
      }
      if (l15 == 0) {
        int row = m * 16 + quad * 4 + r;
        sPart[wave][row][0] = p;
        sPart[wave][row][1] = q;
      }
    }
  __syncthreads();

#pragma unroll
  for (int m = 0; m < 4; ++m)
#pragma unroll
    for (int r = 0; r < 4; ++r) {
      int row = m * 16 + quad * 4 + r;
      float ts  = sPart[0][row][0] + sPart[1][row][0] + sPart[2][row][0] + sPart[3][row][0];
      float tss = sPart[0][row][1] + sPart[1][row][1] + sPart[2][row][1] + sPart[3][row][1];
      float mu  = ts * 0.0078125f;
      float var = tss * 0.0078125f - mu * mu;
      var = var > 0.f ? var : 0.f;
      float rstd = rsqrtf(var + 1e-5f);
      int node = nb + row;
      if (node < N_NODES) {
#pragma unroll
        for (int i = 0; i < 2; ++i) {
          int f = (2 * wave + i) * 16 + l15;
          float o = (acc[i][m][r] - mu) * rstd * gamma[f] + beta[f];
          outN[(size_t)node * ND + f] = o;
        }
      }
    }
}

extern "C" void kernel_launch(void* const* d_in, const int* in_sizes, int n_in,
                              void* d_out, int out_size, void* d_ws, size_t ws_size,
                              hipStream_t stream)
{
  const float* nf  = (const float*)d_in[0];
  const float* ef  = (const float*)d_in[1];
  const void*  ei  = d_in[2];
  const float* Wm1 = (const float*)d_in[3];
  const float* bm1 = (const float*)d_in[4];
  const float* Wm2 = (const float*)d_in[5];
  const float* bm2 = (const float*)d_in[6];
  const float* Wm3 = (const float*)d_in[7];
  const float* bm3 = (const float*)d_in[8];
  const float* We1 = (const float*)d_in[9];
  const float* be1 = (const float*)d_in[10];
  const float* We2 = (const float*)d_in[11];
  const float* be2 = (const float*)d_in[12];
  const float* Wn  = (const float*)d_in[13];
  const float* bn  = (const float*)d_in[14];
  const float* gamma = (const float*)d_in[15];
  const float* beta  = (const float*)d_in[16];

  float* outN = (float*)d_out;                           // [50000,128] f32
  float* outE = outN + (size_t)N_NODES * ND;             // [400000,64] f32
  float* msg  = outN;  // f32 accumulator in outN region (block-diagonal reuse)

  const bool haveW  = ws_size >= (size_t)(2u * WS_WEND);
  const bool haveNF = ws_size >= (size_t)WS_FULL_BYTES;
  u16* ws = (u16*)d_ws;
  const u16* nfb = ws + WS_NFB;

  hipMemsetAsync(msg, 0, (size_t)N_NODES * MD * sizeof(float), stream);

  if (haveW) {
    prep_weights<<<(WS_WEND + 255) / 256, 256, 0, stream>>>(
        Wm1, Wm2, Wm3, We1, We2, Wn, ws);
    if (haveNF)
      prep_nf<<<(N_NODES * ND / 8 + 255) / 256, 256, 0, stream>>>(nf, ws + WS_NFB);
  }

  const int egrid = N_EDGES / ET;
  const int ngrid = (N_NODES + ET - 1) / ET;

  if (haveW && haveNF) {
    edge_fused_kernel<true, true><<<egrid, 256, 0, stream>>>(
        nf, nfb, ef, ei,
        ws + WS_WM1, bm1, ws + WS_WM2, bm2, ws + WS_WM3, bm3,
        ws + WS_WE1, be1, ws + WS_WE2, be2, msg, outE);
    node_kernel<true, true><<<ngrid, 256, 0, stream>>>(
        nf, nfb, msg, ws + WS_WN, bn, gamma, beta, outN);
  } else if (haveW) {
    edge_fused_kernel<true, false><<<egrid, 256, 0, stream>>>(
        nf, nullptr, ef, ei,
        ws + WS_WM1, bm1, ws + WS_WM2, bm2, ws + WS_WM3, bm3,
        ws + WS_WE1, be1, ws + WS_WE2, be2, msg, outE);
    node_kernel<true, false><<<ngrid, 256, 0, stream>>>(
        nf, nullptr, msg, ws + WS_WN, bn, gamma, beta, outN);
  } else {
    edge_fused_kernel<false, false><<<egrid, 256, 0, stream>>>(
        nf, nullptr, ef, ei,
        Wm1, bm1, Wm2, bm2, Wm3, bm3, We1, be1, We2, be2, msg, outE);
    node_kernel<false, false><<<ngrid, 256, 0, stream>>>(
        nf, nullptr, msg, Wn, bn, gamma, beta, outN);
  }
}